// Round 6
// baseline (92.168 us; speedup 1.0000x reference)
//
#include <hip/hip_runtime.h>
#include <math.h>

#define NPTS   4096
#define BATCH  16
#define BLK    512
#define CS     4                         // column splits
#define COLS_PER_BLK (NPTS / CS)         // 1024
#define TPB    (COLS_PER_BLK / 32)       // 32 col tiles per block
#define ROWS_PER_BLK 512                 // 8 waves x 2 row-tiles x 32 rows
#define PANELS (NPTS / ROWS_PER_BLK)     // 8

typedef __attribute__((ext_vector_type(8)))  short bf16x8;
typedef __attribute__((ext_vector_type(16))) float f32x16;

static __device__ __forceinline__ unsigned short f2bf(float x) {
    unsigned u = __float_as_uint(x);
    unsigned r = 0x7FFFu + ((u >> 16) & 1u);     // RNE
    return (unsigned short)((u + r) >> 16);
}
static __device__ __forceinline__ float bf2f(unsigned short h) {
    return __uint_as_float(((unsigned)h) << 16);
}

// ---------------------------------------------------------------------------
// One mfma_f32_32x32x16_bf16 per 32x32 tile = full distance sub-matrix
// (k-slot map validated rounds 4/5, absmax 0.0):
//   k0-2: A=-2ph,B=th  k3-5: A=-2pl,B=th  k6-8: A=-2ph,B=tl
//   k9,10: A=pph,ppl B=1   k11,12: A=1 B=tth,ttl   k13-15: 0
// Both chamfer directions run as ROW-min sweeps (grid z = dir, A/B swapped):
// no col-min extraction, no LDS/global atomics, no sentinel memset.
// ws: float partial[dir][b][cs][4096] (2 MB), every slot written exactly once.
// ---------------------------------------------------------------------------

static __device__ __forceinline__ bf16x8 make_afrag(const float* mp, int l) {
    const short one = (short)0x3F80;
    float x = mp[0], y = mp[1], z = mp[2];
    unsigned short hx = f2bf(x), hy = f2bf(y), hz = f2bf(z);
    unsigned short lx = f2bf(x - bf2f(hx));
    unsigned short ly = f2bf(y - bf2f(hy));
    unsigned short lz = f2bf(z - bf2f(hz));
    unsigned short n2hx = f2bf(-2.0f * bf2f(hx));
    unsigned short n2hy = f2bf(-2.0f * bf2f(hy));
    unsigned short n2hz = f2bf(-2.0f * bf2f(hz));
    unsigned short n2lx = f2bf(-2.0f * bf2f(lx));
    unsigned short n2ly = f2bf(-2.0f * bf2f(ly));
    unsigned short n2lz = f2bf(-2.0f * bf2f(lz));
    float pp = fmaf(z, z, fmaf(y, y, x * x));
    unsigned short pph = f2bf(pp);
    unsigned short ppl = f2bf(pp - bf2f(pph));
    if (l < 32)
        return (bf16x8){(short)n2hx, (short)n2hy, (short)n2hz,
                        (short)n2lx, (short)n2ly, (short)n2lz,
                        (short)n2hx, (short)n2hy};
    else
        return (bf16x8){(short)n2hz, (short)pph, (short)ppl, one, one, 0, 0, 0};
}

__global__ __launch_bounds__(BLK) void chamfer_mfma(
    const float* __restrict__ pred, const float* __restrict__ target,
    float* __restrict__ partial)
{
    __shared__ __align__(16) bf16x8 sB[TPB * 64];   // 32 KB B-fragments

    const int bx    = blockIdx.x;
    const int cs    = bx & (CS - 1);
    const int panel = bx >> 2;
    const int b     = blockIdx.y;
    const int dir   = blockIdx.z;
    const int t     = threadIdx.x;
    const int w     = t >> 6;
    const int l     = t & 63;
    const short one = (short)0x3F80;

    const float* mine  = dir ? target : pred;
    const float* other = dir ? pred : target;

    // ---- stage B fragments for this block's 1024 columns ----
    const int colbase = cs * COLS_PER_BLK;
    for (int e = t; e < TPB * 64; e += BLK) {
        const int el   = e & 63;
        const int tile = e >> 6;
        const int col  = colbase + tile * 32 + (el & 31);
        const float* tp = other + ((size_t)b * NPTS + col) * 3;
        float x = tp[0], y = tp[1], z = tp[2];
        unsigned short hx = f2bf(x), hy = f2bf(y), hz = f2bf(z);
        unsigned short lx = f2bf(x - bf2f(hx));
        unsigned short ly = f2bf(y - bf2f(hy));
        unsigned short lz = f2bf(z - bf2f(hz));
        float tt = fmaf(z, z, fmaf(y, y, x * x));
        unsigned short th = f2bf(tt);
        unsigned short tl = f2bf(tt - bf2f(th));
        bf16x8 v;
        if (el < 32)
            v = (bf16x8){(short)hx, (short)hy, (short)hz,
                         (short)hx, (short)hy, (short)hz,
                         (short)lx, (short)ly};
        else
            v = (bf16x8){(short)lz, one, one, (short)th, (short)tl, 0, 0, 0};
        sB[e] = v;
    }

    // ---- A fragments: this wave's 2 row-tiles (64 rows) ----
    const int rowbase = panel * ROWS_PER_BLK + w * 64;
    const size_t mb = (size_t)b * NPTS;
    bf16x8 af[2];
    #pragma unroll
    for (int j = 0; j < 2; ++j)
        af[j] = make_afrag(mine + (mb + rowbase + j * 32 + (l & 31)) * 3, l);

    __syncthreads();

    f32x16 rm[2];
    #pragma unroll
    for (int j = 0; j < 2; ++j)
        #pragma unroll
        for (int i = 0; i < 16; ++i) rm[j][i] = INFINITY;

    f32x16 zacc;
    #pragma unroll
    for (int i = 0; i < 16; ++i) zacc[i] = 0.0f;

    // ---- sweep col tiles: 1 ds_read + 2 MFMA + 32 v_min per tile ----
    for (int tile = 0; tile < TPB; ++tile) {
        bf16x8 bft = sB[tile * 64 + l];
        f32x16 a0 = __builtin_amdgcn_mfma_f32_32x32x16_bf16(af[0], bft, zacc, 0, 0, 0);
        f32x16 a1 = __builtin_amdgcn_mfma_f32_32x32x16_bf16(af[1], bft, zacc, 0, 0, 0);
        #pragma unroll
        for (int i = 0; i < 16; ++i) rm[0][i] = fminf(rm[0][i], a0[i]);
        #pragma unroll
        for (int i = 0; i < 16; ++i) rm[1][i] = fminf(rm[1][i], a1[i]);
    }

    // ---- rowmin: reduce across the 32 col-lanes of each half, store ----
    const int h = l >> 5;
    float* pb = partial + (((size_t)dir * BATCH + b) * CS + cs) * NPTS;
    #pragma unroll
    for (int j = 0; j < 2; ++j) {
        #pragma unroll
        for (int i = 0; i < 16; ++i) {
            float v = rm[j][i];
            v = fminf(v, __shfl_xor(v, 1, 64));
            v = fminf(v, __shfl_xor(v, 2, 64));
            v = fminf(v, __shfl_xor(v, 4, 64));
            v = fminf(v, __shfl_xor(v, 8, 64));
            v = fminf(v, __shfl_xor(v, 16, 64));
            rm[j][i] = v;
        }
        if ((l & 31) == 0) {
            #pragma unroll
            for (int i = 0; i < 16; ++i) {
                const int row = rowbase + j * 32 + (i & 3) + 8 * (i >> 2) + 4 * h;
                pb[row] = rm[j][i];
            }
        }
    }
}

// min over CS column-split partials, clamp, sum, scale, atomicAdd out.
__global__ __launch_bounds__(256) void chamfer_sum(
    const float* __restrict__ partial, float* __restrict__ out)
{
    __shared__ float wsum[4];
    const int gid = blockIdx.x * 256 + threadIdx.x;   // 32 blocks = 8192 threads

    float s = 0.0f;
    for (int i = gid; i < 2 * BATCH * NPTS; i += 8192) {
        const int db  = i >> 12;           // (dir, b) pair 0..31
        const int row = i & (NPTS - 1);
        const float* p = partial + (size_t)db * CS * NPTS + row;
        float v = fminf(fminf(p[0], p[NPTS]), fminf(p[2 * NPTS], p[3 * NPTS]));
        s += fmaxf(v, 0.0f);
    }

    #pragma unroll
    for (int off = 32; off > 0; off >>= 1)
        s += __shfl_down(s, off, 64);

    if ((threadIdx.x & 63) == 0) wsum[threadIdx.x >> 6] = s;
    __syncthreads();

    if (threadIdx.x == 0) {
        float acc = wsum[0] + wsum[1] + wsum[2] + wsum[3];
        atomicAdd(out, acc * (1.0f / ((float)BATCH * (float)NPTS)));
    }
}

extern "C" void kernel_launch(void* const* d_in, const int* in_sizes, int n_in,
                              void* d_out, int out_size, void* d_ws, size_t ws_size,
                              hipStream_t stream) {
    const float* pred   = (const float*)d_in[0];
    const float* target = (const float*)d_in[1];
    float* out = (float*)d_out;
    float* partial = (float*)d_ws;                    // 2 MB, fully overwritten

    hipMemsetAsync(out, 0, sizeof(float), stream);

    chamfer_mfma<<<dim3(CS * PANELS, BATCH, 2), BLK, 0, stream>>>(
        pred, target, partial);
    chamfer_sum<<<dim3(32), 256, 0, stream>>>(partial, out);
}